// Round 4
// baseline (278.122 us; speedup 1.0000x reference)
//
#include <hip/hip_runtime.h>
#include <math.h>

#define NB 16
#define NN 1024
#define NH 32
#define NW 32
#define ND 256
#define NPIX (NB*NH*NW)        // 16384

// output layout (floats): z_q [16,256,32,32] | kl | indices [16,32,32] | perplexity
#define ZQ_OFF  0
#define KL_OFF  4194304
#define IDX_OFF 4194305
#define PPL_OFF 4210689

#define LGAMMA_1024F 6071.2804f
#define BS_ROW_B 2080          // 16 rows x 1040 f16; chunk c at (c ^ (row&7))

typedef _Float16 f16x8 __attribute__((ext_vector_type(8)));
typedef _Float16 f16x4 __attribute__((ext_vector_type(4)));
typedef float    f32x4 __attribute__((ext_vector_type(4)));

__device__ __forceinline__ float fast_rcp(float x){ return __builtin_amdgcn_rcpf(x); }

// lgamma+digamma for a in [1, ~8]: shift by 3, Stirling at z=a+3 (z>=4).
__device__ __forceinline__ void lgamma_digamma(float a, float& lg, float& dg){
    float a1 = a + 1.f, a2 = a + 2.f, z = a + 3.f;
    float t12  = a1*a2;
    float prod = a*t12;
    float rz = fast_rcp(z);
    float rp = fast_rcp(prod);
    float lz = __logf(z);
    float lp = __logf(prod);
    float rz2 = rz*rz;
    lg = (z - 0.5f)*lz - z + 0.918938533f
       + rz*(0.083333333f - 0.002777778f*rz2) - lp;
    float sr = (t12 + a*(a + a + 3.f))*rp;
    dg = lz - 0.5f*rz - rz2*(0.083333333f - 0.008333333f*rz2) - sr;
}

// one element: alpha, stats accumulation, e = (a/ln u)^2 (fp32, unnormalized)
__device__ __forceinline__ float elem(float x, float u,
                                      float& S, float& L, float& P){
    float t  = __expf(-fabsf(x));
    float a  = fmaxf(x, 0.f) + __logf(1.f + t) + 1.f;
    float lg, dg;
    lgamma_digamma(a, lg, dg);
    S += a; L += lg; P += (a - 1.f)*dg;
    float d = 1.f - u;
    float lup = -d*(1.f + d*(0.5f + d*(0.33333333f + d*(0.25f
              + d*(0.2f + d*(0.16666667f + d*0.14285714f))))));
    float lu = (d < 0.09f) ? lup : __logf(u);
    float ar = a * fast_rcp(lu);
    return ar*ar;
}

// ---------------------------------------------------------------------------
// k_tr: cb [1024n][256d] f32 -> cbT[kb][d][32kk] f16, natural K-order.
// ---------------------------------------------------------------------------
__global__ __launch_bounds__(256) void k_tr(
    const float* __restrict__ cb, _Float16* __restrict__ cbT)
{
    const int kb = blockIdx.x, kq = blockIdx.y, d = threadIdx.x;
    _Float16 tmp[8];
#pragma unroll
    for (int i = 0; i < 8; ++i)
        tmp[i] = (_Float16)cb[(size_t)(32*kb + 8*kq + i)*ND + d];
    *(f16x8*)(cbT + (size_t)kb*8192 + (size_t)d*32 + 8*kq) = *(f16x8*)tmp;
}

// ---------------------------------------------------------------------------
// k_mega: 1024 threads, 16 pixels, 64 n-lane-groups/pixel.
// Thread owns n = 256k + 4*nq + m, nq = 4v+j4 in [0,64), k<4, m<4.
// Ends with: padded-atomic colsum, atomic klsum, last-block ppl/kl finalize.
// ---------------------------------------------------------------------------
__global__ __launch_bounds__(1024, 4) void k_mega(
    const float* __restrict__ logits, const float* __restrict__ noise,
    const _Float16* __restrict__ cbT, float* __restrict__ colsumP,
    float* __restrict__ klsum, unsigned int* __restrict__ done,
    float* __restrict__ out)
{
    __shared__ __align__(16) char lds[16*BS_ROW_B + 6*256*4];
    char*  bsb  = lds;
    float* redS = (float*)(lds + 16*BS_ROW_B);   // [16][16]
    float* redL = redS + 256;
    float* redP = redL + 256;
    float* redZ = redP + 256;
    float* redM = redZ + 256;
    int*   redI = (int*)(redM + 256);

    const int t    = threadIdx.x;
    const int row  = blockIdx.x >> 1;            // b*32 + h
    const int w0   = (blockIdx.x & 1) * 16;
    const int b    = row >> 5, h = row & 31;
    const int lane = t & 63;
    const int v    = t >> 6;                     // wave 0..15
    const int wl   = lane & 15;                  // pixel-in-block
    const int j4   = (lane >> 4) & 3;            // 0..3
    const int p    = row*32 + w0 + wl;
    const int nq   = 4*v + j4;                   // 0..63; n = 256k + 4*nq + m

    const float* lgB = logits + (size_t)b*(NN*NH*NW) + (size_t)(4*nq)*(NH*NW)
                     + (size_t)h*NW + w0 + wl;
    const float* nzB = noise  + (size_t)p*NN + 4*nq;

    float4 u4[4];
    float  xs[4][4];
    float  ev[16];
    // 2-way split accumulators (halve serial FP chains)
    float Sa = 0.f, La = 0.f, Pa = 0.f, Za = 0.f;
    float Sb = 0.f, Lb = 0.f, Pb = 0.f, Zb = 0.f;
    float mxA = -1.f, mxB = -1.f;
    int   idxA = 0, idxB = 0;

#define CHUNK_LOAD(kk) do{                                        \
    u4[kk] = *(const float4*)(nzB + 256*(kk));                    \
    xs[kk][0] = lgB[(size_t)(256*(kk)+0)*(NH*NW)];                \
    xs[kk][1] = lgB[(size_t)(256*(kk)+1)*(NH*NW)];                \
    xs[kk][2] = lgB[(size_t)(256*(kk)+2)*(NH*NW)];                \
    xs[kk][3] = lgB[(size_t)(256*(kk)+3)*(NH*NW)]; }while(0)

#define DO_EA(kk,mm,UC) do{                                       \
    float e = elem(xs[kk][mm], UC, Sa, La, Pa);                   \
    Za += e;                                                      \
    if (e > mxA){ mxA = e; idxA = 256*(kk) + 4*nq + (mm); }       \
    ev[4*(kk)+(mm)] = e; }while(0)

#define DO_EB(kk,mm,UC) do{                                       \
    float e = elem(xs[kk][mm], UC, Sb, Lb, Pb);                   \
    Zb += e;                                                      \
    if (e > mxB){ mxB = e; idxB = 256*(kk) + 4*nq + (mm); }       \
    ev[4*(kk)+(mm)] = e; }while(0)

    CHUNK_LOAD(0); CHUNK_LOAD(1);
    __builtin_amdgcn_sched_barrier(0);
#pragma unroll
    for (int k = 0; k < 4; ++k){
        if (k < 2){ CHUNK_LOAD(k+2); __builtin_amdgcn_sched_barrier(0); }
        DO_EA(k,0,u4[k].x);
        DO_EB(k,1,u4[k].y);
        DO_EA(k,2,u4[k].z);
        DO_EB(k,3,u4[k].w);
    }
#undef CHUNK_LOAD
#undef DO_EA
#undef DO_EB

    // merge the two accumulator sets
    float S = Sa + Sb, L = La + Lb, P = Pa + Pb, Z = Za + Zb;
    float mx = mxA; int idx = idxA;
    {
        bool take = (mxB > mxA) || (mxB == mxA && idxB < idxA);
        mx  = take ? mxB : mxA;
        idx = take ? idxB : idxA;
    }

    // reduce over the 4 j4-lanes of this pixel within the wave
#pragma unroll
    for (int mask = 16; mask < 64; mask <<= 1){
        S += __shfl_xor(S, mask);
        L += __shfl_xor(L, mask);
        P += __shfl_xor(P, mask);
        Z += __shfl_xor(Z, mask);
        float mo = __shfl_xor(mx, mask);
        int   io = __shfl_xor(idx, mask);
        bool take = (mo > mx) || (mo == mx && io < idx);
        mx  = take ? mo : mx;
        idx = take ? io : idx;
    }
    if (j4 == 0){
        redS[16*v + wl] = S;  redL[16*v + wl] = L;
        redP[16*v + wl] = P;  redZ[16*v + wl] = Z;
        redM[16*v + wl] = mx; redI[16*v + wl] = idx;
    }
    __syncthreads();

    // every thread: full Z for its pixel (16 broadcast LDS reads)
    float Zt = 0.f;
#pragma unroll
    for (int qz = 0; qz < 16; ++qz) Zt += redZ[16*qz + wl];
    const float zinv = fast_rcp(Zt);

    // write normalized f16 sample to Bs as 8B ds_write_b64:
    // n = 256k + 4*nq + m -> chunk c = 32k + (nq>>1), sub byte = 8*(nq&1)+2m
    {
        char* brow = bsb + wl*BS_ROW_B;
        const int sw   = wl & 7;
        const int sub8 = (nq & 1) << 3;
        const int cb2  = nq >> 1;
#pragma unroll
        for (int k = 0; k < 4; ++k){
            f16x4 hv;
            hv[0] = (_Float16)(ev[4*k+0]*zinv);
            hv[1] = (_Float16)(ev[4*k+1]*zinv);
            hv[2] = (_Float16)(ev[4*k+2]*zinv);
            hv[3] = (_Float16)(ev[4*k+3]*zinv);
            *(f16x4*)(brow + (((32*k + cb2) ^ sw) << 4) + sub8) = hv;
        }
    }
    __syncthreads();   // Bs complete

    // ---- GEMM: D[d][pix] = cbT(d,K)*Bs(pix,K); wave v -> d in [16v,16v+16) ----
    const _Float16* aBase = cbT + (size_t)(16*v + wl)*32 + j4*8;
    const char* bRow = bsb + wl*BS_ROW_B;
    const int fsw = wl & 7;

    f32x4 acc = (f32x4)0.f;
    f16x8 ar[4];
    ar[0] = *(const f16x8*)(aBase);
    ar[1] = *(const f16x8*)(aBase + 8192);
    ar[2] = *(const f16x8*)(aBase + 2*8192);
    __builtin_amdgcn_sched_barrier(0);

#pragma unroll
    for (int kb = 0; kb < 32; ++kb){
        if (kb + 3 < 32){
            ar[(kb+3)&3] = *(const f16x8*)(aBase + (size_t)(kb+3)*8192);
            __builtin_amdgcn_sched_barrier(0);
        }
        f16x8 bf = *(const f16x8*)(bRow + ((((kb << 2) | j4) ^ fsw) << 4));
        acc = __builtin_amdgcn_mfma_f32_16x16x32_f16(ar[kb&3], bf, acc, 0, 0, 0);
    }

    float* outp = out + (size_t)b*(ND*1024) + h*32 + w0;
#pragma unroll
    for (int r = 0; r < 4; ++r){
        int d = 16*v + 4*j4 + r;
        outp[(size_t)d*1024 + wl] = acc[r];
    }

    // ---- colsum for this block: thread t sums column t, padded atomic ----
    {
        float s0 = 0.f;
#pragma unroll
        for (int r = 0; r < 16; ++r){
            const char* br = bsb + r*BS_ROW_B;
            const int sw2 = r & 7;
            s0 += (float)*(const _Float16*)(br + ((((t >> 3) ^ sw2) << 4) + 2*(t & 7)));
        }
        atomicAdd(&colsumP[(size_t)t*32], s0);
    }

    // per-pixel finalize: kl, argmax index
    if (t < 16){
        float Sq = 0.f, Lq = 0.f, Pq = 0.f, M = -1.f;
        int I = 0x7fffffff;
#pragma unroll
        for (int qz = 0; qz < 16; ++qz){
            Sq += redS[16*qz + t]; Lq += redL[16*qz + t]; Pq += redP[16*qz + t];
            float m = redM[16*qz + t]; int i = redI[16*qz + t];
            bool take = (m > M) || (m == M && i < I);
            M = take ? m : M; I = take ? i : I;
        }
        out[IDX_OFF + row*32 + w0 + t] = (float)I;
        float rS  = fast_rcp(Sq);
        float lnS = __logf(Sq);
        float lgS = (Sq - 0.5f)*lnS - Sq + 0.918938533f + 0.083333333f*rS;
        float dgS = lnS - 0.5f*rS;
        float kl = lgS - Lq - LGAMMA_1024F + (Pq - dgS*(Sq - 1024.f));
#pragma unroll
        for (int mask = 1; mask < 16; mask <<= 1) kl += __shfl_xor(kl, mask);
        if (t == 0) atomicAdd(klsum, kl);
    }

    // ---- last-block finalize: ppl + kl_loss ----
    __syncthreads();   // drains all this block's global atomics (vmcnt(0))
    int* flag = (int*)redZ;   // redZ no longer needed
    if (t == 0){
        __threadfence();
        unsigned int old = atomicAdd(done, 1u);
        *flag = (old == 1023u) ? 1 : 0;
    }
    __syncthreads();
    if (*flag){
        __threadfence();   // acquire: invalidate L1 before reading colsumP/klsum
        float cv = __hip_atomic_load(&colsumP[(size_t)t*32],
                                     __ATOMIC_RELAXED, __HIP_MEMORY_SCOPE_AGENT);
        float avg = cv * (1.f/16384.f);
        float s = avg * logf(avg + 1e-10f);
#pragma unroll
        for (int mask = 1; mask < 64; mask <<= 1) s += __shfl_xor(s, mask);
        if (lane == 0) redL[v] = s;
        __syncthreads();
        if (t == 0){
            float tot = 0.f;
#pragma unroll
            for (int i = 0; i < 16; ++i) tot += redL[i];
            float kv = __hip_atomic_load(klsum, __ATOMIC_RELAXED,
                                         __HIP_MEMORY_SCOPE_AGENT);
            out[PPL_OFF] = expf(-tot);
            out[KL_OFF]  = 1e-3f * (kv * (1.f/16384.f));
        }
    }
}

extern "C" void kernel_launch(void* const* d_in, const int* in_sizes, int n_in,
                              void* d_out, int out_size, void* d_ws, size_t ws_size,
                              hipStream_t stream)
{
    const float* logits = (const float*)d_in[0];
    const float* cb     = (const float*)d_in[1];
    const float* noise  = (const float*)d_in[2];
    float* out = (float*)d_out;

    float* colsumP      = (float*)d_ws;                  // 1024 x 32-float stride = 128KB
    float* klsum        = colsumP + (size_t)1024*32;     // [32768]
    unsigned int* done  = (unsigned int*)(klsum + 1);    // [32769]
    _Float16* cbT       = (_Float16*)((float*)d_ws + 32772);  // 16B-aligned, 512KB

    hipMemsetAsync(d_ws, 0, 32770u*sizeof(float), stream);
    k_tr   <<<dim3(32, 4), 256, 0, stream>>>(cb, cbT);
    k_mega <<<dim3(1024), 1024, 0, stream>>>(logits, noise, cbT,
                                             colsumP, klsum, done, out);
}

// Round 5
// 204.518 us; speedup vs baseline: 1.3599x; 1.3599x over previous
//
#include <hip/hip_runtime.h>
#include <math.h>

#define NB 16
#define NN 1024
#define NH 32
#define NW 32
#define ND 256
#define NPIX (NB*NH*NW)        // 16384

// output layout (floats): z_q [16,256,32,32] | kl | indices [16,32,32] | perplexity
#define ZQ_OFF  0
#define KL_OFF  4194304
#define IDX_OFF 4194305
#define PPL_OFF 4210689

#define LGAMMA_1024F 6071.2804f
#define BS_ROW_B 2080          // 16 rows x 1040 f16; chunk c at (c ^ (row&7))

typedef _Float16 f16x8 __attribute__((ext_vector_type(8)));
typedef _Float16 f16x4 __attribute__((ext_vector_type(4)));
typedef float    f32x4 __attribute__((ext_vector_type(4)));

__device__ __forceinline__ float fast_rcp(float x){ return __builtin_amdgcn_rcpf(x); }

// lgamma+digamma for a in [1, ~8]: shift by 3, Stirling at z=a+3 (z>=4).
__device__ __forceinline__ void lgamma_digamma(float a, float& lg, float& dg){
    float a1 = a + 1.f, a2 = a + 2.f, z = a + 3.f;
    float t12  = a1*a2;
    float prod = a*t12;
    float rz = fast_rcp(z);
    float rp = fast_rcp(prod);
    float lz = __logf(z);
    float lp = __logf(prod);
    float rz2 = rz*rz;
    lg = (z - 0.5f)*lz - z + 0.918938533f
       + rz*(0.083333333f - 0.002777778f*rz2) - lp;
    float sr = (t12 + a*(a + a + 3.f))*rp;
    dg = lz - 0.5f*rz - rz2*(0.083333333f - 0.008333333f*rz2) - sr;
}

// one element: alpha, stats accumulation, e = (a/ln u)^2 (fp32, unnormalized)
__device__ __forceinline__ float elem(float x, float u,
                                      float& S, float& L, float& P){
    float t  = __expf(-fabsf(x));
    float a  = fmaxf(x, 0.f) + __logf(1.f + t) + 1.f;
    float lg, dg;
    lgamma_digamma(a, lg, dg);
    S += a; L += lg; P += (a - 1.f)*dg;
    float d = 1.f - u;
    float lup = -d*(1.f + d*(0.5f + d*(0.33333333f + d*(0.25f
              + d*(0.2f + d*(0.16666667f + d*0.14285714f))))));
    float lu = (d < 0.09f) ? lup : __logf(u);
    float ar = a * fast_rcp(lu);
    return ar*ar;
}

// ---------------------------------------------------------------------------
// k_tr: cb [1024n][256d] f32 -> cbT[kb][d][32kk] f16, natural K-order.
// ---------------------------------------------------------------------------
__global__ __launch_bounds__(256) void k_tr(
    const float* __restrict__ cb, _Float16* __restrict__ cbT)
{
    const int kb = blockIdx.x, kq = blockIdx.y, d = threadIdx.x;
    _Float16 tmp[8];
#pragma unroll
    for (int i = 0; i < 8; ++i)
        tmp[i] = (_Float16)cb[(size_t)(32*kb + 8*kq + i)*ND + d];
    *(f16x8*)(cbT + (size_t)kb*8192 + (size_t)d*32 + 8*kq) = *(f16x8*)tmp;
}

// ---------------------------------------------------------------------------
// k_mega: 1024 threads, 16 pixels, 64 n-lane-groups/pixel.
// Thread owns n = 256k + 4*nq + m, nq = 4v+j4 in [0,64), k<4, m<4.
// Phase-1 loads are asm-pinned: all 20 issued up-front (4x dwordx4 noise,
// 16x dword logits), consumed under hand-counted s_waitcnt vmcnt(N).
// ---------------------------------------------------------------------------
__global__ __launch_bounds__(1024, 2) void k_mega(
    const float* __restrict__ logits, const float* __restrict__ noise,
    const _Float16* __restrict__ cbT, float* __restrict__ colpart,
    float* __restrict__ klpart, float* __restrict__ out)
{
    __shared__ __align__(16) char lds[16*BS_ROW_B + 6*256*4];
    char*  bsb  = lds;
    float* redS = (float*)(lds + 16*BS_ROW_B);   // [16][16]
    float* redL = redS + 256;
    float* redP = redL + 256;
    float* redZ = redP + 256;
    float* redM = redZ + 256;
    int*   redI = (int*)(redM + 256);

    const int t    = threadIdx.x;
    const int row  = blockIdx.x >> 1;            // b*32 + h
    const int w0   = (blockIdx.x & 1) * 16;
    const int b    = row >> 5, h = row & 31;
    const int lane = t & 63;
    const int v    = t >> 6;                     // wave 0..15
    const int wl   = lane & 15;                  // pixel-in-block
    const int j4   = (lane >> 4) & 3;            // 0..3
    const int p    = row*32 + w0 + wl;
    const int nq   = 4*v + j4;                   // 0..63; n = 256k + 4*nq + m

    const float* lgB = logits + (size_t)b*(NN*NH*NW) + (size_t)(4*nq)*(NH*NW)
                     + (size_t)h*NW + w0 + wl;
    const float* nzB = noise  + (size_t)p*NN + 4*nq;

    f32x4 u0, u1, u2, u3;
    float x00,x01,x02,x03, x10,x11,x12,x13;
    float x20,x21,x22,x23, x30,x31,x32,x33;
    float ev[16];
    // 2-way split accumulators (halve serial FP chains)
    float Sa = 0.f, La = 0.f, Pa = 0.f, Za = 0.f;
    float Sb = 0.f, Lb = 0.f, Pb = 0.f, Zb = 0.f;
    float mxA = -1.f, mxB = -1.f;
    int   idxA = 0, idxB = 0;

    // ---- issue ALL phase-1 loads (asm: cannot be sunk/split) ----
    asm volatile(
        "global_load_dwordx4 %0, %4, off\n\t"
        "global_load_dwordx4 %1, %4, off offset:1024\n\t"
        "global_load_dwordx4 %2, %4, off offset:2048\n\t"
        "global_load_dwordx4 %3, %4, off offset:3072"
        : "=&v"(u0), "=&v"(u1), "=&v"(u2), "=&v"(u3)
        : "v"(nzB));

    // logits chunk k: elems at lgB + (256k+m)*1024 floats, m=0..3
    // bases at +4096B and +12288B, loads at offset:-4096 / offset:0
#define LG_ASM(X0,X1,X2,X3,KK) \
    asm volatile( \
        "global_load_dword %0, %4, off offset:-4096\n\t" \
        "global_load_dword %1, %4, off\n\t" \
        "global_load_dword %2, %5, off offset:-4096\n\t" \
        "global_load_dword %3, %5, off" \
        : "=&v"(X0), "=&v"(X1), "=&v"(X2), "=&v"(X3) \
        : "v"(lgB + (size_t)(256*(KK))*1024 + 1024), \
          "v"(lgB + (size_t)(256*(KK))*1024 + 3072))

    LG_ASM(x00,x01,x02,x03, 0);
    LG_ASM(x10,x11,x12,x13, 1);
    LG_ASM(x20,x21,x22,x23, 2);
    LG_ASM(x30,x31,x32,x33, 3);
#undef LG_ASM

#define WAITV(NSTR) do{ asm volatile("s_waitcnt vmcnt(" NSTR ")"); \
                        __builtin_amdgcn_sched_barrier(0); }while(0)

#define DO_EA(kk,mm,X,UC) do{                                     \
    float e = elem(X, UC, Sa, La, Pa);                            \
    Za += e;                                                      \
    if (e > mxA){ mxA = e; idxA = 256*(kk) + 4*nq + (mm); }       \
    ev[4*(kk)+(mm)] = e; }while(0)

#define DO_EB(kk,mm,X,UC) do{                                     \
    float e = elem(X, UC, Sb, Lb, Pb);                            \
    Zb += e;                                                      \
    if (e > mxB){ mxB = e; idxB = 256*(kk) + 4*nq + (mm); }       \
    ev[4*(kk)+(mm)] = e; }while(0)

    WAITV("12");   // noise#0 + lg chunk0 (loads 0,4-7) complete
    DO_EA(0,0,x00,u0[0]); DO_EB(0,1,x01,u0[1]);
    DO_EA(0,2,x02,u0[2]); DO_EB(0,3,x03,u0[3]);
    WAITV("8");    // noise#1 + lg chunk1 complete
    DO_EA(1,0,x10,u1[0]); DO_EB(1,1,x11,u1[1]);
    DO_EA(1,2,x12,u1[2]); DO_EB(1,3,x13,u1[3]);
    WAITV("4");
    DO_EA(2,0,x20,u2[0]); DO_EB(2,1,x21,u2[1]);
    DO_EA(2,2,x22,u2[2]); DO_EB(2,3,x23,u2[3]);
    WAITV("0");
    DO_EA(3,0,x30,u3[0]); DO_EB(3,1,x31,u3[1]);
    DO_EA(3,2,x32,u3[2]); DO_EB(3,3,x33,u3[3]);
#undef WAITV
#undef DO_EA
#undef DO_EB

    // merge the two accumulator sets
    float S = Sa + Sb, L = La + Lb, P = Pa + Pb, Z = Za + Zb;
    float mx; int idx;
    {
        bool take = (mxB > mxA) || (mxB == mxA && idxB < idxA);
        mx  = take ? mxB : mxA;
        idx = take ? idxB : idxA;
    }

    // reduce over the 4 j4-lanes of this pixel within the wave
#pragma unroll
    for (int mask = 16; mask < 64; mask <<= 1){
        S += __shfl_xor(S, mask);
        L += __shfl_xor(L, mask);
        P += __shfl_xor(P, mask);
        Z += __shfl_xor(Z, mask);
        float mo = __shfl_xor(mx, mask);
        int   io = __shfl_xor(idx, mask);
        bool take = (mo > mx) || (mo == mx && io < idx);
        mx  = take ? mo : mx;
        idx = take ? io : idx;
    }
    if (j4 == 0){
        redS[16*v + wl] = S;  redL[16*v + wl] = L;
        redP[16*v + wl] = P;  redZ[16*v + wl] = Z;
        redM[16*v + wl] = mx; redI[16*v + wl] = idx;
    }
    __syncthreads();

    // every thread: full Z for its pixel (16 broadcast LDS reads)
    float Zt = 0.f;
#pragma unroll
    for (int qz = 0; qz < 16; ++qz) Zt += redZ[16*qz + wl];
    const float zinv = fast_rcp(Zt);

    // write normalized f16 sample to Bs as 8B ds_write_b64:
    // n = 256k + 4*nq + m -> chunk c = 32k + (nq>>1), sub byte = 8*(nq&1)+2m
    {
        char* brow = bsb + wl*BS_ROW_B;
        const int sw   = wl & 7;
        const int sub8 = (nq & 1) << 3;
        const int cb2  = nq >> 1;
#pragma unroll
        for (int k = 0; k < 4; ++k){
            f16x4 hv;
            hv[0] = (_Float16)(ev[4*k+0]*zinv);
            hv[1] = (_Float16)(ev[4*k+1]*zinv);
            hv[2] = (_Float16)(ev[4*k+2]*zinv);
            hv[3] = (_Float16)(ev[4*k+3]*zinv);
            *(f16x4*)(brow + (((32*k + cb2) ^ sw) << 4) + sub8) = hv;
        }
    }
    __syncthreads();   // Bs complete

    // ---- GEMM: D[d][pix] = cbT(d,K)*Bs(pix,K); wave v -> d in [16v,16v+16) ----
    const _Float16* aBase = cbT + (size_t)(16*v + wl)*32 + j4*8;
    const char* bRow = bsb + wl*BS_ROW_B;
    const int fsw = wl & 7;

    f32x4 acc = (f32x4)0.f;
    f16x8 ar[4];
    ar[0] = *(const f16x8*)(aBase);
    ar[1] = *(const f16x8*)(aBase + 8192);
    ar[2] = *(const f16x8*)(aBase + 2*8192);
    __builtin_amdgcn_sched_barrier(0);

#pragma unroll
    for (int kb = 0; kb < 32; ++kb){
        if (kb + 3 < 32){
            ar[(kb+3)&3] = *(const f16x8*)(aBase + (size_t)(kb+3)*8192);
            __builtin_amdgcn_sched_barrier(0);
        }
        f16x8 bf = *(const f16x8*)(bRow + ((((kb << 2) | j4) ^ fsw) << 4));
        acc = __builtin_amdgcn_mfma_f32_16x16x32_f16(ar[kb&3], bf, acc, 0, 0, 0);
    }

    float* outp = out + (size_t)b*(ND*1024) + h*32 + w0;
#pragma unroll
    for (int r = 0; r < 4; ++r){
        int d = 16*v + 4*j4 + r;
        outp[(size_t)d*1024 + wl] = acc[r];
    }

    // ---- colsum row for this block: thread t sums column t ----
    {
        float s0 = 0.f;
#pragma unroll
        for (int r = 0; r < 16; ++r){
            const char* br = bsb + r*BS_ROW_B;
            const int sw2 = r & 7;
            s0 += (float)*(const _Float16*)(br + ((((t >> 3) ^ sw2) << 4) + 2*(t & 7)));
        }
        colpart[(size_t)blockIdx.x*NN + t] = s0;
    }

    // per-pixel finalize: kl, argmax index (off the barrier critical path)
    if (t < 16){
        float Sq = 0.f, Lq = 0.f, Pq = 0.f, M = -1.f;
        int I = 0x7fffffff;
#pragma unroll
        for (int qz = 0; qz < 16; ++qz){
            Sq += redS[16*qz + t]; Lq += redL[16*qz + t]; Pq += redP[16*qz + t];
            float m = redM[16*qz + t]; int i = redI[16*qz + t];
            bool take = (m > M) || (m == M && i < I);
            M = take ? m : M; I = take ? i : I;
        }
        out[IDX_OFF + row*32 + w0 + t] = (float)I;
        float rS  = fast_rcp(Sq);
        float lnS = __logf(Sq);
        float lgS = (Sq - 0.5f)*lnS - Sq + 0.918938533f + 0.083333333f*rS;
        float dgS = lnS - 0.5f*rS;
        float kl = lgS - Lq - LGAMMA_1024F + (Pq - dgS*(Sq - 1024.f));
#pragma unroll
        for (int mask = 1; mask < 16; mask <<= 1) kl += __shfl_xor(kl, mask);
        if (t == 0) klpart[blockIdx.x] = kl;
    }
}

// ---------------------------------------------------------------------------
// k_red: colsum[n] = sum over 1024 colpart rows. Atomic-free: 32 blocks,
// each owns 32 n-columns fully; 8 row-segments reduced through LDS.
// ---------------------------------------------------------------------------
__global__ __launch_bounds__(256) void k_red(
    const float* __restrict__ colpart, float* __restrict__ colsum)
{
    __shared__ float red[8][32];
    const int nl = threadIdx.x & 31;
    const int rs = threadIdx.x >> 5;             // 0..7
    const int n  = blockIdx.x*32 + nl;
    const float* cp = colpart + (size_t)rs*128*NN + n;
    float s = 0.f;
#pragma unroll 8
    for (int r = 0; r < 128; ++r)
        s += cp[(size_t)r*NN];
    red[rs][nl] = s;
    __syncthreads();
    if (threadIdx.x < 32){
        float tot = 0.f;
#pragma unroll
        for (int i = 0; i < 8; ++i) tot += red[i][threadIdx.x];
        colsum[blockIdx.x*32 + threadIdx.x] = tot;
    }
}

// ---------------------------------------------------------------------------
// k_final: kl_loss (from klpart[1024]) + perplexity (from colsum[1024])
// ---------------------------------------------------------------------------
__global__ __launch_bounds__(256) void k_final(
    const float* __restrict__ colsum, const float* __restrict__ klpart,
    float* __restrict__ out)
{
    __shared__ float red[8];
    const int tid = threadIdx.x;
    float s = 0.f, kls = 0.f;
#pragma unroll
    for (int n = tid; n < NN; n += 256){
        float avg = colsum[n] * (1.f/16384.f);
        s += avg * logf(avg + 1e-10f);
        kls += klpart[n];
    }
#pragma unroll
    for (int mask = 1; mask < 64; mask <<= 1){
        s   += __shfl_xor(s, mask);
        kls += __shfl_xor(kls, mask);
    }
    if ((tid & 63) == 0){ red[tid >> 6] = s; red[4 + (tid >> 6)] = kls; }
    __syncthreads();
    if (tid == 0){
        float tot = red[0] + red[1] + red[2] + red[3];
        float klt = red[4] + red[5] + red[6] + red[7];
        out[PPL_OFF] = expf(-tot);
        out[KL_OFF]  = 1e-3f * (klt * (1.f/16384.f));
    }
}

extern "C" void kernel_launch(void* const* d_in, const int* in_sizes, int n_in,
                              void* d_out, int out_size, void* d_ws, size_t ws_size,
                              hipStream_t stream)
{
    const float* logits = (const float*)d_in[0];
    const float* cb     = (const float*)d_in[1];
    const float* noise  = (const float*)d_in[2];
    float* out = (float*)d_out;

    float* colpart = (float*)d_ws;                       // 1024*1024 f32 = 4 MB
    float* colsum  = colpart + (size_t)1024*NN;          // 1024
    float* klpart  = colsum + NN;                        // 1024
    _Float16* cbT  = (_Float16*)(klpart + NN);           // 512 KB (16B-aligned)

    k_tr   <<<dim3(32, 4), 256, 0, stream>>>(cb, cbT);
    k_mega <<<dim3(1024), 1024, 0, stream>>>(logits, noise, cbT, colpart, klpart, out);
    k_red  <<<dim3(32),    256, 0, stream>>>(colpart, colsum);
    k_final<<<1, 256, 0, stream>>>(colsum, klpart, out);
}